// Round 9
// baseline (487.290 us; speedup 1.0000x reference)
//
#include <hip/hip_runtime.h>
#include <hip/hip_bf16.h>
#include <math.h>

typedef __attribute__((ext_vector_type(16))) float f32x16;
typedef __attribute__((ext_vector_type(4)))  int   int4v;

#define MFMA8(A, B, C) __builtin_amdgcn_mfma_f32_32x32x16_fp8_fp8((long)(A), (long)(B), (C), 0, 0, 0)

__device__ __forceinline__ int pk4(float a, float b, float c, float d) {
    int w = __builtin_amdgcn_cvt_pk_fp8_f32(a, b, 0, false);   // bytes 0,1
    w = __builtin_amdgcn_cvt_pk_fp8_f32(c, d, w, true);        // bytes 2,3
    return w;
}
__device__ __forceinline__ unsigned long long mk64(unsigned lo32, unsigned hi32) {
    return ((unsigned long long)hi32 << 32) | lo32;
}

// ---------------- ws layout (bytes) ----------------
// Weight pack is laid out EXACTLY as the kernel's LDS image (102400 B), swizzled:
//   [0, 65536)      W1: 8B frag at (m*32 + (kc^(m&31)))*8,  m 0..255, kc 0..31
//                      frag bytes i = fp8(W1[(kc*8+i)*256 + m] * 16)
//   [65536, 98304)  W2: 8B frag at 65536 + (m*32 + (kc^(m&31)))*8, m 0..127
//                      frag bytes i = fp8(W2[(kc*8+i)*128 + m] * 16)
//   [98304, 102400) B3: 8B frag at 98304 + (m*16 + (kc^(m&15)))*8, m 0..31, kc 0..15
//                      m<8: fp8(W3[k*8+m]*8); 8<=m<16: fp8(AV[(m-8)*128+k]); else 0
//   [102400, 102432) v2 : float[8] = sum_k AV[c][k]^2
//   [102432, 103456) b1p: float[256] epilogue-order b1
//   [103456, 103968) b2p: float[128] epilogue-order b2

__global__ void prep_pack(const float* __restrict__ W1, const float* __restrict__ W2,
                          const float* __restrict__ W3, const float* __restrict__ AV,
                          char* __restrict__ wp) {
    int j = blockIdx.x * 256 + threadIdx.x;   // one 8-byte fragment per thread
    float f[8];
    if (j < 8192) {                            // W1: j = m*32 + slot
        int m = j >> 5, slot = j & 31, kc = slot ^ (m & 31);
        #pragma unroll
        for (int i = 0; i < 8; ++i) f[i] = W1[(kc * 8 + i) * 256 + m] * 16.f;
        int2 t; t.x = pk4(f[0], f[1], f[2], f[3]); t.y = pk4(f[4], f[5], f[6], f[7]);
        *(int2*)(wp + (size_t)j * 8) = t;
    } else if (j < 12288) {                    // W2
        int jj = j - 8192; int m = jj >> 5, slot = jj & 31, kc = slot ^ (m & 31);
        #pragma unroll
        for (int i = 0; i < 8; ++i) f[i] = W2[(kc * 8 + i) * 128 + m] * 16.f;
        int2 t; t.x = pk4(f[0], f[1], f[2], f[3]); t.y = pk4(f[4], f[5], f[6], f[7]);
        *(int2*)(wp + 65536 + (size_t)jj * 8) = t;
    } else if (j < 12800) {                    // B3
        int jj = j - 12288; int m = jj >> 4, slot = jj & 15, kc = slot ^ (m & 15);
        #pragma unroll
        for (int i = 0; i < 8; ++i) {
            int k = kc * 8 + i;
            float v = 0.f;
            if (m < 8)       v = W3[k * 8 + m] * 8.f;
            else if (m < 16) v = AV[(m - 8) * 128 + k];
            f[i] = v;
        }
        int2 t; t.x = pk4(f[0], f[1], f[2], f[3]); t.y = pk4(f[4], f[5], f[6], f[7]);
        *(int2*)(wp + 98304 + (size_t)jj * 8) = t;
    }
}

__global__ void prep_small(const float* __restrict__ AV, const float* __restrict__ b1,
                           const float* __restrict__ b2, float* __restrict__ v2,
                           float* __restrict__ b1p, float* __restrict__ b2p) {
    int t = threadIdx.x;   // 256 threads
    {
        int mt = t >> 5, g = (t >> 4) & 1, r = t & 15;
        b1p[t] = b1[mt * 32 + 4 * g + (r & 3) + 8 * (r >> 2)];
    }
    if (t < 128) {
        int mt = t >> 5, g = (t >> 4) & 1, r = t & 15;
        b2p[t] = b2[mt * 32 + 4 * g + (r & 3) + 8 * (r >> 2)];
    }
    if (t < 64) {
        int c = t >> 3, jj = t & 7;
        float s = 0.f;
        for (int k = jj * 16; k < jj * 16 + 16; ++k) { float a = AV[c * 128 + k]; s = fmaf(a, a, s); }
        s += __shfl_xor(s, 1); s += __shfl_xor(s, 2); s += __shfl_xor(s, 4);
        if (jj == 0) v2[c] = s;
    }
}

// ---------------- main fused kernel ----------------
// 256 blocks x 1024 threads (16 waves/CU). All weights resident in LDS (100KB),
// preloaded once; then each wave INDEPENDENTLY processes 2 tasks of 32 rows:
//   - x B-frags loaded directly from global (lane lo = batch row row0+lo,
//     g half = k-slice), converted to fp8 in-register. No x staging, no barrier.
//   - GEMM1: 8 m-tiles x 16 K-steps, A from LDS (ds_read_b64); h packed to fp8
//     in registers (hq[8][4] ints).
//   - GEMM2 B-frags assembled from hq with one shfl_xor(32) per frag:
//     frag(ktt,g) = (g0's Q[ktt>>1][(2ktt+g)&3], g1's same) per the verified
//     C/D layout row = (r&3)+8*(r>>2)+4g.
//   - GEMM2: 4 m-tiles; act packed to aq[4][4]; a2 = own + shfl_xor partner.
//   - GEMM3: 8 K-steps on assembled act frags; OpenMax epilogue per wave.
// Zero __syncthreads after preload; no inter-wave dependencies.
__global__ __launch_bounds__(1024, 4)
void openmax_fused(const float* __restrict__ x,
                   const float* __restrict__ b3,
                   const float* __restrict__ walpha, const float* __restrict__ wbeta,
                   const float* __restrict__ wtau,
                   const char* __restrict__ wpack, const float* __restrict__ v2g,
                   const float* __restrict__ b1p, const float* __restrict__ b2p,
                   float* __restrict__ out) {
    __shared__ __align__(16) char smem[102400];
    const int tid = threadIdx.x;
    const int wv = tid >> 6, l = tid & 63;
    const int lo = l & 31, g = l >> 5;

    // ---- preload all weights to LDS (straight copy; layout matches) ----
    {
        const int4v* src = (const int4v*)wpack;
        int4v* dst = (int4v*)smem;
        for (int i = tid; i < 6400; i += 1024) dst[i] = src[i];
    }
    __syncthreads();

    #pragma unroll 1
    for (int task = 0; task < 2; ++task) {
        const long row0 = ((long)(blockIdx.x * 16 + wv) * 2 + task) * 32;
        const float* xr = x + (row0 + lo) * 256 + g * 8;

        // ---- x B-frags: lane's own row, 16 K-steps x 8 floats -> fp8 ----
        unsigned long long bx[16];
        #pragma unroll
        for (int ktt = 0; ktt < 16; ++ktt) {
            float4 u = *(const float4*)(xr + ktt * 16);
            float4 v = *(const float4*)(xr + ktt * 16 + 4);
            bx[ktt] = mk64((unsigned)pk4(u.x, u.y, u.z, u.w),
                           (unsigned)pk4(v.x, v.y, v.z, v.w));
        }

        // ---- GEMM1: h^T = W1 @ x^T (8 m-tiles), pack h to fp8 regs ----
        unsigned hq[8][4];
        #pragma unroll
        for (int mt = 0; mt < 8; ++mt) {
            f32x16 acc;
            #pragma unroll
            for (int i = 0; i < 16; ++i) acc[i] = 0.f;
            #pragma unroll
            for (int ktt = 0; ktt < 16; ++ktt) {
                unsigned long long A = *(const unsigned long long*)
                    (smem + (((mt * 32 + lo) * 32 + ((2 * ktt + g) ^ lo)) << 3));
                acc = MFMA8(A, bx[ktt], acc);
            }
            const float* bp = b1p + mt * 32 + g * 16;
            float bia[16];
            *(float4*)(bia)      = *(const float4*)(bp);
            *(float4*)(bia + 4)  = *(const float4*)(bp + 4);
            *(float4*)(bia + 8)  = *(const float4*)(bp + 8);
            *(float4*)(bia + 12) = *(const float4*)(bp + 12);
            #pragma unroll
            for (int q = 0; q < 4; ++q) {
                float v0 = fmaxf(fmaf(acc[4 * q + 0], 0.0625f, bia[4 * q + 0]), 0.f);
                float v1 = fmaxf(fmaf(acc[4 * q + 1], 0.0625f, bia[4 * q + 1]), 0.f);
                float v2_ = fmaxf(fmaf(acc[4 * q + 2], 0.0625f, bia[4 * q + 2]), 0.f);
                float v3 = fmaxf(fmaf(acc[4 * q + 3], 0.0625f, bia[4 * q + 3]), 0.f);
                hq[mt][q] = (unsigned)pk4(v0, v1, v2_, v3);
            }
        }

        // ---- assemble GEMM2 B-frags: one shfl_xor(32) each ----
        unsigned long long bh[16];
        #pragma unroll
        for (int ktt = 0; ktt < 16; ++ktt) {
            const int mth = ktt >> 1, q0 = (ktt & 1) * 2;
            unsigned m0 = hq[mth][q0], m1 = hq[mth][q0 + 1];
            unsigned snd = g ? m0 : m1;
            unsigned rcv = (unsigned)__shfl_xor((int)snd, 32);
            bh[ktt] = g ? mk64(rcv, m1) : mk64(m0, rcv);
        }

        // ---- GEMM2: act^T = W2 @ h (4 m-tiles); pack act, a2 partial ----
        unsigned aq[4][4];
        float ss = 0.f;
        #pragma unroll
        for (int mt = 0; mt < 4; ++mt) {
            f32x16 acc;
            #pragma unroll
            for (int i = 0; i < 16; ++i) acc[i] = 0.f;
            #pragma unroll
            for (int ktt = 0; ktt < 16; ++ktt) {
                unsigned long long A = *(const unsigned long long*)
                    (smem + 65536 + (((mt * 32 + lo) * 32 + ((2 * ktt + g) ^ lo)) << 3));
                acc = MFMA8(A, bh[ktt], acc);
            }
            const float* bp = b2p + mt * 32 + g * 16;
            float bia[16];
            *(float4*)(bia)      = *(const float4*)(bp);
            *(float4*)(bia + 4)  = *(const float4*)(bp + 4);
            *(float4*)(bia + 8)  = *(const float4*)(bp + 8);
            *(float4*)(bia + 12) = *(const float4*)(bp + 12);
            #pragma unroll
            for (int q = 0; q < 4; ++q) {
                float v0 = fmaxf(fmaf(acc[4 * q + 0], 0.0625f, bia[4 * q + 0]), 0.f);
                float v1 = fmaxf(fmaf(acc[4 * q + 1], 0.0625f, bia[4 * q + 1]), 0.f);
                float v2_ = fmaxf(fmaf(acc[4 * q + 2], 0.0625f, bia[4 * q + 2]), 0.f);
                float v3 = fmaxf(fmaf(acc[4 * q + 3], 0.0625f, bia[4 * q + 3]), 0.f);
                ss += v0 * v0 + v1 * v1 + v2_ * v2_ + v3 * v3;
                aq[mt][q] = (unsigned)pk4(v0, v1, v2_, v3);
            }
        }

        // ---- assemble GEMM3 B-frags ----
        unsigned long long ba[8];
        #pragma unroll
        for (int ktt = 0; ktt < 8; ++ktt) {
            const int mth = ktt >> 1, q0 = (ktt & 1) * 2;
            unsigned m0 = aq[mth][q0], m1 = aq[mth][q0 + 1];
            unsigned snd = g ? m0 : m1;
            unsigned rcv = (unsigned)__shfl_xor((int)snd, 32);
            ba[ktt] = g ? mk64(rcv, m1) : mk64(m0, rcv);
        }

        // ---- GEMM3: [logits*8 ; dots] = B3 @ act ----
        f32x16 acc3;
        #pragma unroll
        for (int i = 0; i < 16; ++i) acc3[i] = 0.f;
        #pragma unroll
        for (int ktt = 0; ktt < 8; ++ktt) {
            unsigned long long A = *(const unsigned long long*)
                (smem + 98304 + ((lo * 16 + ((2 * ktt + g) ^ (lo & 15))) << 3));
            acc3 = MFMA8(A, ba[ktt], acc3);
        }

        // ---- OpenMax epilogue (per wave) ----
        float oth[8];
        #pragma unroll
        for (int j = 0; j < 8; ++j) oth[j] = __shfl_xor(acc3[j], 32);
        float a2v = ss + __shfl_xor(ss, 32);

        float4 e_b3[2], e_v2[2], e_al[2], e_be[2], e_ta[2];
        e_b3[0] = *(const float4*)(b3);     e_b3[1] = *(const float4*)(b3 + 4);
        e_v2[0] = *(const float4*)(v2g);    e_v2[1] = *(const float4*)(v2g + 4);
        e_al[0] = *(const float4*)(walpha); e_al[1] = *(const float4*)(walpha + 4);
        e_be[0] = *(const float4*)(wbeta);  e_be[1] = *(const float4*)(wbeta + 4);
        e_ta[0] = *(const float4*)(wtau);   e_ta[1] = *(const float4*)(wtau + 4);

        float m = 0.f, outv[8];
        #pragma unroll
        for (int c = 0; c < 8; ++c) {
            float lgv = ((c >> 2) == g) ? acc3[c & 3]       : oth[c & 3];      // x8 scaled
            float dtv = ((c >> 2) == g) ? acc3[4 + (c & 3)] : oth[4 + (c & 3)];
            float v2c = e_v2[c >> 2][c & 3];
            float d2 = a2v - 2.f * dtv + v2c;
            float dist = sqrtf(fmaxf(d2, 0.f));
            float sb = fmaxf(e_be[c >> 2][c & 3], 1e-6f);
            float sx = fmaxf(dist - e_ta[c >> 2][c & 3], 0.f);
            float t = sx / sb;
            float y = exp2f(e_al[c >> 2][c & 3] * log2f(t));   // t^alpha (t=0 -> 0)
            float cdf = 1.f - expf(-y);
            m = fmaxf(m, cdf);
            outv[c] = fmaf(lgv, 0.125f, e_b3[c >> 2][c & 3]);  // unscale W3 x8
        }
        float scale = (m > 0.5f) ? (1.f - m) : 1.f;
        if (g == 0) {
            float4 o0 = { outv[0] * scale, outv[1] * scale, outv[2] * scale, outv[3] * scale };
            float4 o1 = { outv[4] * scale, outv[5] * scale, outv[6] * scale, outv[7] * scale };
            float4* op = (float4*)(out + (row0 + lo) * 8);
            op[0] = o0; op[1] = o1;
        }
    }
}

extern "C" void kernel_launch(void* const* d_in, const int* in_sizes, int n_in,
                              void* d_out, int out_size, void* d_ws, size_t ws_size,
                              hipStream_t stream) {
    const float* x      = (const float*)d_in[0];
    const float* W1     = (const float*)d_in[1];
    const float* b1     = (const float*)d_in[2];
    const float* W2     = (const float*)d_in[3];
    const float* b2     = (const float*)d_in[4];
    const float* W3     = (const float*)d_in[5];
    const float* b3     = (const float*)d_in[6];
    const float* walpha = (const float*)d_in[7];
    const float* wbeta  = (const float*)d_in[8];
    const float* wtau   = (const float*)d_in[9];
    const float* AV     = (const float*)d_in[10];
    float* out = (float*)d_out;

    char*  wpack = (char*)d_ws;
    float* v2    = (float*)((char*)d_ws + 102400);
    float* b1p   = (float*)((char*)d_ws + 102432);
    float* b2p   = (float*)((char*)d_ws + 103456);

    prep_pack<<<50, 256, 0, stream>>>(W1, W2, W3, AV, wpack);
    prep_small<<<1, 256, 0, stream>>>(AV, b1, b2, v2, b1p, b2p);

    const int B = in_sizes[0] / 256;   // 262144 rows
    const int nblk = B / 1024;         // 256 blocks, 16 waves each, 2 tasks/wave
    openmax_fused<<<nblk, 1024, 0, stream>>>(x, b3, walpha, wbeta, wtau,
                                             wpack, v2, b1p, b2p, out);
}

// Round 10
// 487.044 us; speedup vs baseline: 1.0005x; 1.0005x over previous
//
#include <hip/hip_runtime.h>
#include <hip/hip_bf16.h>
#include <math.h>

typedef __attribute__((ext_vector_type(16))) float f32x16;
typedef __attribute__((ext_vector_type(4)))  int   int4v;

#define MFMA8(A, B, C) __builtin_amdgcn_mfma_f32_32x32x16_fp8_fp8((long)(A), (long)(B), (C), 0, 0, 0)

__device__ __forceinline__ int pk4(float a, float b, float c, float d) {
    int w = __builtin_amdgcn_cvt_pk_fp8_f32(a, b, 0, false);   // bytes 0,1
    w = __builtin_amdgcn_cvt_pk_fp8_f32(c, d, w, true);        // bytes 2,3
    return w;
}
__device__ __forceinline__ unsigned long long mk64(unsigned lo32, unsigned hi32) {
    return ((unsigned long long)hi32 << 32) | lo32;
}

// ---------------- ws layout (bytes) ----------------
// Weight pack laid out EXACTLY as the kernel's LDS image (102400 B), swizzled:
//   [0, 65536)      W1: 8B frag at (m*32 + (kc^(m&31)))*8,  m 0..255, kc 0..31
//                      frag bytes i = fp8(W1[(kc*8+i)*256 + m] * 16)
//   [65536, 98304)  W2: 8B frag at 65536 + (m*32 + (kc^(m&31)))*8, m 0..127
//   [98304, 102400) B3: 8B frag at 98304 + (m*16 + (kc^(m&15)))*8, m 0..31, kc 0..15
//                      m<8: fp8(W3[k*8+m]*8); 8<=m<16: fp8(AV[(m-8)*128+k]); else 0
//   [102400, 102432) v2 : float[8] = sum_k AV[c][k]^2
//   [102432, 103456) b1p: float[256] epilogue-order b1
//   [103456, 103968) b2p: float[128] epilogue-order b2

__global__ void prep_pack(const float* __restrict__ W1, const float* __restrict__ W2,
                          const float* __restrict__ W3, const float* __restrict__ AV,
                          char* __restrict__ wp) {
    int j = blockIdx.x * 256 + threadIdx.x;   // one 8-byte fragment per thread
    float f[8];
    if (j < 8192) {                            // W1: j = m*32 + slot
        int m = j >> 5, slot = j & 31, kc = slot ^ (m & 31);
        #pragma unroll
        for (int i = 0; i < 8; ++i) f[i] = W1[(kc * 8 + i) * 256 + m] * 16.f;
        int2 t; t.x = pk4(f[0], f[1], f[2], f[3]); t.y = pk4(f[4], f[5], f[6], f[7]);
        *(int2*)(wp + (size_t)j * 8) = t;
    } else if (j < 12288) {                    // W2
        int jj = j - 8192; int m = jj >> 5, slot = jj & 31, kc = slot ^ (m & 31);
        #pragma unroll
        for (int i = 0; i < 8; ++i) f[i] = W2[(kc * 8 + i) * 128 + m] * 16.f;
        int2 t; t.x = pk4(f[0], f[1], f[2], f[3]); t.y = pk4(f[4], f[5], f[6], f[7]);
        *(int2*)(wp + 65536 + (size_t)jj * 8) = t;
    } else if (j < 12800) {                    // B3
        int jj = j - 12288; int m = jj >> 4, slot = jj & 15, kc = slot ^ (m & 15);
        #pragma unroll
        for (int i = 0; i < 8; ++i) {
            int k = kc * 8 + i;
            float v = 0.f;
            if (m < 8)       v = W3[k * 8 + m] * 8.f;
            else if (m < 16) v = AV[(m - 8) * 128 + k];
            f[i] = v;
        }
        int2 t; t.x = pk4(f[0], f[1], f[2], f[3]); t.y = pk4(f[4], f[5], f[6], f[7]);
        *(int2*)(wp + 98304 + (size_t)jj * 8) = t;
    }
}

__global__ void prep_small(const float* __restrict__ AV, const float* __restrict__ b1,
                           const float* __restrict__ b2, float* __restrict__ v2,
                           float* __restrict__ b1p, float* __restrict__ b2p) {
    int t = threadIdx.x;   // 256 threads
    {
        int mt = t >> 5, g = (t >> 4) & 1, r = t & 15;
        b1p[t] = b1[mt * 32 + 4 * g + (r & 3) + 8 * (r >> 2)];
    }
    if (t < 128) {
        int mt = t >> 5, g = (t >> 4) & 1, r = t & 15;
        b2p[t] = b2[mt * 32 + 4 * g + (r & 3) + 8 * (r >> 2)];
    }
    if (t < 64) {
        int c = t >> 3, jj = t & 7;
        float s = 0.f;
        for (int k = jj * 16; k < jj * 16 + 16; ++k) { float a = AV[c * 128 + k]; s = fmaf(a, a, s); }
        s += __shfl_xor(s, 1); s += __shfl_xor(s, 2); s += __shfl_xor(s, 4);
        if (jj == 0) v2[c] = s;
    }
}

// ---------------- main fused kernel ----------------
// 256 blocks x 1024 threads; LDS 100KB -> exactly 1 block/CU, 16 waves/CU (50%).
// __launch_bounds__(1024, 1): VGPR budget 128 (R9's (1024,4) forced 64 -> 600MB
// of scratch spills; this is the fix). All weights LDS-resident; each wave
// independently processes 2 tasks of 32 rows; zero barriers after preload.
__global__ __launch_bounds__(1024, 1)
void openmax_fused(const float* __restrict__ x,
                   const float* __restrict__ b3,
                   const float* __restrict__ walpha, const float* __restrict__ wbeta,
                   const float* __restrict__ wtau,
                   const char* __restrict__ wpack, const float* __restrict__ v2g,
                   const float* __restrict__ b1p, const float* __restrict__ b2p,
                   float* __restrict__ out) {
    __shared__ __align__(16) char smem[102400];
    const int tid = threadIdx.x;
    const int wv = tid >> 6, l = tid & 63;
    const int lo = l & 31, g = l >> 5;

    // ---- preload all weights to LDS (straight copy; layout matches) ----
    {
        const int4v* src = (const int4v*)wpack;
        int4v* dst = (int4v*)smem;
        for (int i = tid; i < 6400; i += 1024) dst[i] = src[i];
    }
    __syncthreads();

    #pragma unroll 1
    for (int task = 0; task < 2; ++task) {
        const long row0 = ((long)(blockIdx.x * 16 + wv) * 2 + task) * 32;
        const float* xr = x + (row0 + lo) * 256 + g * 8;

        // ---- x B-frags: lane's own row, 16 K-steps x 8 floats -> fp8 ----
        unsigned long long bx[16];
        #pragma unroll
        for (int ktt = 0; ktt < 16; ++ktt) {
            float4 u = *(const float4*)(xr + ktt * 16);
            float4 v = *(const float4*)(xr + ktt * 16 + 4);
            bx[ktt] = mk64((unsigned)pk4(u.x, u.y, u.z, u.w),
                           (unsigned)pk4(v.x, v.y, v.z, v.w));
        }

        // ---- GEMM1: h^T = W1 @ x^T (8 m-tiles), pack h to fp8 regs ----
        unsigned hq[8][4];
        #pragma unroll
        for (int mt = 0; mt < 8; ++mt) {
            f32x16 acc;
            #pragma unroll
            for (int i = 0; i < 16; ++i) acc[i] = 0.f;
            #pragma unroll
            for (int ktt = 0; ktt < 16; ++ktt) {
                unsigned long long A = *(const unsigned long long*)
                    (smem + (((mt * 32 + lo) * 32 + ((2 * ktt + g) ^ lo)) << 3));
                acc = MFMA8(A, bx[ktt], acc);
            }
            const float* bp = b1p + mt * 32 + g * 16;
            float bia[16];
            *(float4*)(bia)      = *(const float4*)(bp);
            *(float4*)(bia + 4)  = *(const float4*)(bp + 4);
            *(float4*)(bia + 8)  = *(const float4*)(bp + 8);
            *(float4*)(bia + 12) = *(const float4*)(bp + 12);
            #pragma unroll
            for (int q = 0; q < 4; ++q) {
                float v0 = fmaxf(fmaf(acc[4 * q + 0], 0.0625f, bia[4 * q + 0]), 0.f);
                float v1 = fmaxf(fmaf(acc[4 * q + 1], 0.0625f, bia[4 * q + 1]), 0.f);
                float v2_ = fmaxf(fmaf(acc[4 * q + 2], 0.0625f, bia[4 * q + 2]), 0.f);
                float v3 = fmaxf(fmaf(acc[4 * q + 3], 0.0625f, bia[4 * q + 3]), 0.f);
                hq[mt][q] = (unsigned)pk4(v0, v1, v2_, v3);
            }
        }

        // ---- assemble GEMM2 B-frags: one shfl_xor(32) each ----
        unsigned long long bh[16];
        #pragma unroll
        for (int ktt = 0; ktt < 16; ++ktt) {
            const int mth = ktt >> 1, q0 = (ktt & 1) * 2;
            unsigned m0 = hq[mth][q0], m1 = hq[mth][q0 + 1];
            unsigned snd = g ? m0 : m1;
            unsigned rcv = (unsigned)__shfl_xor((int)snd, 32);
            bh[ktt] = g ? mk64(rcv, m1) : mk64(m0, rcv);
        }

        // ---- GEMM2: act^T = W2 @ h (4 m-tiles); pack act, a2 partial ----
        unsigned aq[4][4];
        float ss = 0.f;
        #pragma unroll
        for (int mt = 0; mt < 4; ++mt) {
            f32x16 acc;
            #pragma unroll
            for (int i = 0; i < 16; ++i) acc[i] = 0.f;
            #pragma unroll
            for (int ktt = 0; ktt < 16; ++ktt) {
                unsigned long long A = *(const unsigned long long*)
                    (smem + 65536 + (((mt * 32 + lo) * 32 + ((2 * ktt + g) ^ lo)) << 3));
                acc = MFMA8(A, bh[ktt], acc);
            }
            const float* bp = b2p + mt * 32 + g * 16;
            float bia[16];
            *(float4*)(bia)      = *(const float4*)(bp);
            *(float4*)(bia + 4)  = *(const float4*)(bp + 4);
            *(float4*)(bia + 8)  = *(const float4*)(bp + 8);
            *(float4*)(bia + 12) = *(const float4*)(bp + 12);
            #pragma unroll
            for (int q = 0; q < 4; ++q) {
                float v0 = fmaxf(fmaf(acc[4 * q + 0], 0.0625f, bia[4 * q + 0]), 0.f);
                float v1 = fmaxf(fmaf(acc[4 * q + 1], 0.0625f, bia[4 * q + 1]), 0.f);
                float v2_ = fmaxf(fmaf(acc[4 * q + 2], 0.0625f, bia[4 * q + 2]), 0.f);
                float v3 = fmaxf(fmaf(acc[4 * q + 3], 0.0625f, bia[4 * q + 3]), 0.f);
                ss += v0 * v0 + v1 * v1 + v2_ * v2_ + v3 * v3;
                aq[mt][q] = (unsigned)pk4(v0, v1, v2_, v3);
            }
        }

        // ---- assemble GEMM3 B-frags ----
        unsigned long long ba[8];
        #pragma unroll
        for (int ktt = 0; ktt < 8; ++ktt) {
            const int mth = ktt >> 1, q0 = (ktt & 1) * 2;
            unsigned m0 = aq[mth][q0], m1 = aq[mth][q0 + 1];
            unsigned snd = g ? m0 : m1;
            unsigned rcv = (unsigned)__shfl_xor((int)snd, 32);
            ba[ktt] = g ? mk64(rcv, m1) : mk64(m0, rcv);
        }

        // ---- GEMM3: [logits*8 ; dots] = B3 @ act ----
        f32x16 acc3;
        #pragma unroll
        for (int i = 0; i < 16; ++i) acc3[i] = 0.f;
        #pragma unroll
        for (int ktt = 0; ktt < 8; ++ktt) {
            unsigned long long A = *(const unsigned long long*)
                (smem + 98304 + ((lo * 16 + ((2 * ktt + g) ^ (lo & 15))) << 3));
            acc3 = MFMA8(A, ba[ktt], acc3);
        }

        // ---- OpenMax epilogue (per wave) ----
        float oth[8];
        #pragma unroll
        for (int j = 0; j < 8; ++j) oth[j] = __shfl_xor(acc3[j], 32);
        float a2v = ss + __shfl_xor(ss, 32);

        float4 e_b3[2], e_v2[2], e_al[2], e_be[2], e_ta[2];
        e_b3[0] = *(const float4*)(b3);     e_b3[1] = *(const float4*)(b3 + 4);
        e_v2[0] = *(const float4*)(v2g);    e_v2[1] = *(const float4*)(v2g + 4);
        e_al[0] = *(const float4*)(walpha); e_al[1] = *(const float4*)(walpha + 4);
        e_be[0] = *(const float4*)(wbeta);  e_be[1] = *(const float4*)(wbeta + 4);
        e_ta[0] = *(const float4*)(wtau);   e_ta[1] = *(const float4*)(wtau + 4);

        float m = 0.f, outv[8];
        #pragma unroll
        for (int c = 0; c < 8; ++c) {
            float lgv = ((c >> 2) == g) ? acc3[c & 3]       : oth[c & 3];      // x8 scaled
            float dtv = ((c >> 2) == g) ? acc3[4 + (c & 3)] : oth[4 + (c & 3)];
            float v2c = e_v2[c >> 2][c & 3];
            float d2 = a2v - 2.f * dtv + v2c;
            float dist = sqrtf(fmaxf(d2, 0.f));
            float sb = fmaxf(e_be[c >> 2][c & 3], 1e-6f);
            float sx = fmaxf(dist - e_ta[c >> 2][c & 3], 0.f);
            float t = sx / sb;
            float y = exp2f(e_al[c >> 2][c & 3] * log2f(t));   // t^alpha (t=0 -> 0)
            float cdf = 1.f - expf(-y);
            m = fmaxf(m, cdf);
            outv[c] = fmaf(lgv, 0.125f, e_b3[c >> 2][c & 3]);  // unscale W3 x8
        }
        float scale = (m > 0.5f) ? (1.f - m) : 1.f;
        if (g == 0) {
            float4 o0 = { outv[0] * scale, outv[1] * scale, outv[2] * scale, outv[3] * scale };
            float4 o1 = { outv[4] * scale, outv[5] * scale, outv[6] * scale, outv[7] * scale };
            float4* op = (float4*)(out + (row0 + lo) * 8);
            op[0] = o0; op[1] = o1;
        }
    }
}

extern "C" void kernel_launch(void* const* d_in, const int* in_sizes, int n_in,
                              void* d_out, int out_size, void* d_ws, size_t ws_size,
                              hipStream_t stream) {
    const float* x      = (const float*)d_in[0];
    const float* W1     = (const float*)d_in[1];
    const float* b1     = (const float*)d_in[2];
    const float* W2     = (const float*)d_in[3];
    const float* b2     = (const float*)d_in[4];
    const float* W3     = (const float*)d_in[5];
    const float* b3     = (const float*)d_in[6];
    const float* walpha = (const float*)d_in[7];
    const float* wbeta  = (const float*)d_in[8];
    const float* wtau   = (const float*)d_in[9];
    const float* AV     = (const float*)d_in[10];
    float* out = (float*)d_out;

    char*  wpack = (char*)d_ws;
    float* v2    = (float*)((char*)d_ws + 102400);
    float* b1p   = (float*)((char*)d_ws + 102432);
    float* b2p   = (float*)((char*)d_ws + 103456);

    prep_pack<<<50, 256, 0, stream>>>(W1, W2, W3, AV, wpack);
    prep_small<<<1, 256, 0, stream>>>(AV, b1, b2, v2, b1p, b2p);

    const int B = in_sizes[0] / 256;   // 262144 rows
    const int nblk = B / 1024;         // 256 blocks, 16 waves each, 2 tasks/wave
    openmax_fused<<<nblk, 1024, 0, stream>>>(x, b3, walpha, wbeta, wtau,
                                             wpack, v2, b1p, b2p, out);
}